// Round 1
// 549.232 us; speedup vs baseline: 1.0606x; 1.0606x over previous
//
#include <hip/hip_runtime.h>
#include <hip/hip_bf16.h>

typedef __attribute__((ext_vector_type(8))) short bf16x8;
typedef __attribute__((ext_vector_type(4))) float f32x4;

#define PCAP 768   // max points per p3 block (batch_len/split + slack)

// async 16B global->LDS copy (per-lane global src, wave-uniform LDS base + lane*16)
__device__ __forceinline__ void async_copy16(const void* g, void* l)
{
    __builtin_amdgcn_global_load_lds(
        (const __attribute__((address_space(1))) unsigned int*)g,
        (__attribute__((address_space(3))) unsigned int*)l, 16, 0, 0);
}

// ---------------- Phase 0: pre-split conv_w into frag-ready hi/lo bf16 ----------------
__global__ void p0_wsplit(const float* __restrict__ convw,
                          short* __restrict__ whi, short* __restrict__ wlo)
{
    int e = blockIdx.x * 256 + threadIdx.x;
    if (e >= 2048) return;
    int lane = e & 63;
    int kstep = (e >> 6) & 7;
    int nt = e >> 9;
    int cluster = nt * 16 + (lane & 15);
    int ch0 = kstep * 32 + (lane >> 4) * 8;
    const float* src = convw + cluster * 256 + ch0;
    #pragma unroll
    for (int j = 0; j < 8; ++j) {
        float x = src[j];
        unsigned u = __float_as_uint(x);
        unsigned uh = u & 0xffff0000u;
        float r = x - __uint_as_float(uh);
        whi[e * 8 + j] = (short)(u >> 16);
        wlo[e * 8 + j] = (short)(__float_as_uint(r) >> 16);
    }
}

// ---------------- Phase 1: fused norm + logits (split-bf16 MFMA) + softmax ----------------
// v2: latency fix. feat staged to LDS via async global_load_lds, double-buffered
// 64pt x 64ch chunks (16 KB each). XOR-swizzled source so ds_read_b128 is bank-balanced.
// Weight frags loaded to VGPRs BEFORE the async stage issue (older in vmcnt order ->
// compiler waits vmcnt(4), the staging DMAs stay in flight across the MFMAs).
__global__ __launch_bounds__(256, 3) void p1_mfma(
    const float* __restrict__ feat, const int* __restrict__ bids,
    const short* __restrict__ whi, const short* __restrict__ wlo,
    const float* __restrict__ convb,
    float* __restrict__ soft, float* __restrict__ invn, int* __restrict__ cnts, int N)
{
    __shared__ float xbuf[2][4096];   // 2 x 16KB: 64 pts x 64 ch, swizzled
    __shared__ int cnt[8];
    const int t = threadIdx.x;
    if (t < 8) cnt[t] = 0;
    const int w = t >> 6, lane = t & 63;
    const int m = lane & 15, quad = lane >> 4;
    const int p0 = blockIdx.x * 64;

    // staging geometry: LDS 16B-slot s holds (pt = s>>4, inner = (s&15)^(pt&15)),
    // i.e. feat[p0+pt][ck*64 + inner*4 .. +4). slot = pass*256 + t is lane-linear.
    int s_pt[4], s_inner[4];
    #pragma unroll
    for (int pass = 0; pass < 4; ++pass) {
        int slot = pass * 256 + t;
        s_pt[pass] = slot >> 4;
        s_inner[pass] = (slot & 15) ^ (s_pt[pass] & 15);
    }

    auto STAGE = [&](int bi, int ck) {
        #pragma unroll
        for (int pass = 0; pass < 4; ++pass) {
            int gpt = p0 + s_pt[pass];
            const float* src = (gpt < N)
                ? feat + (size_t)gpt * 256 + ck * 64 + s_inner[pass] * 4
                : feat;  // safe dummy row; result masked in epilogue
            async_copy16(src, (char*)&xbuf[bi][0] + (size_t)(pass * 256 + w * 64) * 16);
        }
    };

    STAGE(0, 0);
    __syncthreads();

    f32x4 acc[4];
    #pragma unroll
    for (int nt = 0; nt < 4; ++nt) acc[nt] = (f32x4){0.f, 0.f, 0.f, 0.f};
    float ssq = 0.f;

    const bf16x8* WH = (const bf16x8*)whi;
    const bf16x8* WL = (const bf16x8*)wlo;
    const int ptl = w * 16 + m;   // this lane's point-row within the block tile

    #pragma unroll
    for (int ck = 0; ck < 4; ++ck) {
        // ---- weight frags for this chunk FIRST (must be older than async stage)
        bf16x8 wfh[2][4], wfl[2][4];
        #pragma unroll
        for (int k2 = 0; k2 < 2; ++k2)
            #pragma unroll
            for (int nt = 0; nt < 4; ++nt) {
                wfh[k2][nt] = WH[(nt * 8 + ck * 2 + k2) * 64 + lane];
                wfl[k2][nt] = WL[(nt * 8 + ck * 2 + k2) * 64 + lane];
            }
        __builtin_amdgcn_sched_barrier(0);   // pin: W loads issue before the DMAs
        if (ck < 3) STAGE((ck + 1) & 1, ck + 1);
        __builtin_amdgcn_sched_barrier(0);

        const float* B = &xbuf[ck & 1][0];
        #pragma unroll
        for (int k2 = 0; k2 < 2; ++k2) {
            int i0 = (k2 * 8 + quad * 2 + 0) ^ m;
            int i1 = (k2 * 8 + quad * 2 + 1) ^ m;
            float4 v0 = *(const float4*)(B + (ptl * 16 + i0) * 4);
            float4 v1 = *(const float4*)(B + (ptl * 16 + i1) * 4);
            float x[8] = {v0.x, v0.y, v0.z, v0.w, v1.x, v1.y, v1.z, v1.w};
            bf16x8 ahi, alo;
            #pragma unroll
            for (int j = 0; j < 8; ++j) {
                unsigned u = __float_as_uint(x[j]);
                float r = x[j] - __uint_as_float(u & 0xffff0000u);
                ahi[j] = (short)(u >> 16);
                alo[j] = (short)(__float_as_uint(r) >> 16);
                ssq += x[j] * x[j];
            }
            #pragma unroll
            for (int nt = 0; nt < 4; ++nt) {
                acc[nt] = __builtin_amdgcn_mfma_f32_16x16x32_bf16(ahi, wfh[k2][nt], acc[nt], 0, 0, 0);
                acc[nt] = __builtin_amdgcn_mfma_f32_16x16x32_bf16(ahi, wfl[k2][nt], acc[nt], 0, 0, 0);
                acc[nt] = __builtin_amdgcn_mfma_f32_16x16x32_bf16(alo, wfh[k2][nt], acc[nt], 0, 0, 0);
            }
        }
        if (ck < 3) __syncthreads();   // drains the stage for ck+1; protects buffer reuse
    }

    // ---- ssq: reduce across quads, then transpose via shfl (no LDS, no barrier)
    ssq += __shfl_xor(ssq, 16);
    ssq += __shfl_xor(ssq, 32);   // all lanes now hold ||x||^2 of point (w*16 + m)

    float bias[4];
    #pragma unroll
    for (int nt = 0; nt < 4; ++nt) bias[nt] = convb[nt * 16 + m];

    #pragma unroll
    for (int r = 0; r < 4; ++r) {
        int pl = quad * 4 + r;
        int gpt = p0 + w * 16 + pl;
        float sq = __shfl(ssq, pl);          // lane pl holds point pl's ssq
        float inv = rsqrtf(fmaxf(sq, 1e-24f));
        float v[4];
        #pragma unroll
        for (int nt = 0; nt < 4; ++nt) v[nt] = acc[nt][r] * inv + bias[nt];
        float mx = fmaxf(fmaxf(v[0], v[1]), fmaxf(v[2], v[3]));
        #pragma unroll
        for (int off = 8; off >= 1; off >>= 1) mx = fmaxf(mx, __shfl_xor(mx, off));
        float e[4];
        float s = 0.f;
        #pragma unroll
        for (int nt = 0; nt < 4; ++nt) { e[nt] = __expf(v[nt] - mx); s += e[nt]; }
        #pragma unroll
        for (int off = 8; off >= 1; off >>= 1) s += __shfl_xor(s, off);
        float rs = 1.0f / s;
        if (gpt < N) {
            #pragma unroll
            for (int nt = 0; nt < 4; ++nt)
                soft[(size_t)gpt * 64 + nt * 16 + m] = e[nt] * rs;
            if (m == 0) {
                invn[gpt] = inv;
                atomicAdd(&cnt[bids[gpt]], 1);
            }
        }
    }
    __syncthreads();
    if (t < 8) atomicAdd(&cnts[t], cnt[t]);
}

// ---------------- Phase 2: prefix + counting-sort scatter ----------------
__global__ void p2_offsets(const int* __restrict__ cnts, int* __restrict__ offs, int* __restrict__ cur)
{
    if (threadIdx.x == 0) {
        int acc = 0;
        for (int b = 0; b < 8; ++b) { offs[b] = acc; cur[b] = acc; acc += cnts[b]; }
        offs[8] = acc;
    }
}

__global__ __launch_bounds__(256) void p2_scatter(
    const int* __restrict__ bids, int* __restrict__ cur, int* __restrict__ perm, int N)
{
    __shared__ int lcnt[8], lbase[8];
    const int t = threadIdx.x;
    if (t < 8) lcnt[t] = 0;
    __syncthreads();
    int p = blockIdx.x * 256 + t;
    int b = 0, my = 0;
    bool ok = p < N;
    if (ok) { b = bids[p]; my = atomicAdd(&lcnt[b], 1); }
    __syncthreads();
    if (t < 8) lbase[t] = atomicAdd(&cur[t], lcnt[t]);
    __syncthreads();
    if (ok) perm[lbase[b] + my] = p;
}

// ---------------- Phase 3: per-batch aggregation via split-bf16 MFMA ----------------
// Block = 256 thr = 4 waves; block owns full 64k x 256c tile for (batch b, point-slice sp).
// LDS staged TRANSPOSED ([c][p] / [k][p]) so A/B frags are single b128 reads.
__global__ __launch_bounds__(256) void p3_mfma(
    const float* __restrict__ feat, const float* __restrict__ soft,
    const float* __restrict__ invn, const int* __restrict__ perm,
    const int* __restrict__ offs, float* __restrict__ partial,
    float* __restrict__ S, int split)
{
    __shared__ short xsT_hi[256 * 32];  // [c][p] 16 KB
    __shared__ short xsT_lo[256 * 32];  // 16 KB
    __shared__ short sT_hi[64 * 32];    // [k][p] 4 KB
    __shared__ short sT_lo[64 * 32];    // 4 KB
    __shared__ int   pidxL[PCAP];
    __shared__ float invL[PCAP];

    const int b  = blockIdx.x / split;
    const int sp = blockIdx.x % split;
    const int start = offs[b], end = offs[b + 1];
    const int len = end - start;
    const int chunk = (len + split - 1) / split;
    const int s0 = start + sp * chunk;
    int myLen = end - s0;
    myLen = max(0, min(myLen, chunk));
    myLen = min(myLen, PCAP);

    const int t = threadIdx.x;
    const int w = t >> 6, lane = t & 63;
    const int m = lane & 15, quad = lane >> 4;

    for (int i = t; i < myLen; i += 256) pidxL[i] = perm[s0 + i];
    __syncthreads();
    for (int i = t; i < myLen; i += 256) invL[i] = invn[pidxL[i]];
    __syncthreads();

    f32x4 acc[16];
    #pragma unroll
    for (int ct = 0; ct < 16; ++ct) acc[ct] = (f32x4){0.f, 0.f, 0.f, 0.f};
    float sacc = 0.f;

    const int nch = (myLen + 31) >> 5;
    for (int q = 0; q < nch; ++q) {
        const int p0 = q * 32;
        // per-wave point metadata for its 8-point subgroup
        int pids[8];
        float pinv[8];
        #pragma unroll
        for (int j = 0; j < 8; ++j) {
            int pl = p0 + w * 8 + j;
            bool ok = pl < myLen;
            pids[j] = ok ? pidxL[pl] : -1;
            pinv[j] = ok ? invL[pl] : 0.f;
        }
        // ---- stage x transposed: lane = column c within group, 8 points packed per b128
        #pragma unroll
        for (int cg = 0; cg < 4; ++cg) {
            int c = cg * 64 + lane;
            float vals[8];
            #pragma unroll
            for (int j = 0; j < 8; ++j) {
                float v = 0.f;
                if (pids[j] >= 0) v = feat[(size_t)pids[j] * 256 + c] * pinv[j];
                vals[j] = v;
            }
            bf16x8 vh, vl;
            #pragma unroll
            for (int j = 0; j < 8; ++j) {
                unsigned u = __float_as_uint(vals[j]);
                float r = vals[j] - __uint_as_float(u & 0xffff0000u);
                vh[j] = (short)(u >> 16);
                vl[j] = (short)(__float_as_uint(r) >> 16);
            }
            *(bf16x8*)&xsT_hi[c * 32 + w * 8] = vh;
            *(bf16x8*)&xsT_lo[c * 32 + w * 8] = vl;
        }
        // ---- stage soft transposed: lane = cluster k
        {
            float svals[8];
            #pragma unroll
            for (int j = 0; j < 8; ++j) {
                float v = 0.f;
                if (pids[j] >= 0) v = soft[(size_t)pids[j] * 64 + lane];
                svals[j] = v;
                sacc += v;
            }
            bf16x8 vh, vl;
            #pragma unroll
            for (int j = 0; j < 8; ++j) {
                unsigned u = __float_as_uint(svals[j]);
                float r = svals[j] - __uint_as_float(u & 0xffff0000u);
                vh[j] = (short)(u >> 16);
                vl[j] = (short)(__float_as_uint(r) >> 16);
            }
            *(bf16x8*)&sT_hi[lane * 32 + w * 8] = vh;
            *(bf16x8*)&sT_lo[lane * 32 + w * 8] = vl;
        }
        __syncthreads();
        // ---- compute: A = soft^T (clusters x points), B = x (points x cols)
        bf16x8 ah = *(const bf16x8*)&sT_hi[(w * 16 + m) * 32 + quad * 8];
        bf16x8 al = *(const bf16x8*)&sT_lo[(w * 16 + m) * 32 + quad * 8];
        #pragma unroll
        for (int ct = 0; ct < 16; ++ct) {
            bf16x8 bh = *(const bf16x8*)&xsT_hi[(ct * 16 + m) * 32 + quad * 8];
            bf16x8 bl = *(const bf16x8*)&xsT_lo[(ct * 16 + m) * 32 + quad * 8];
            acc[ct] = __builtin_amdgcn_mfma_f32_16x16x32_bf16(ah, bh, acc[ct], 0, 0, 0);
            acc[ct] = __builtin_amdgcn_mfma_f32_16x16x32_bf16(ah, bl, acc[ct], 0, 0, 0);
            acc[ct] = __builtin_amdgcn_mfma_f32_16x16x32_bf16(al, bh, acc[ct], 0, 0, 0);
        }
        __syncthreads();
    }

    // ---- write this block's partial 64x256 tile (no atomics)
    float* dst = partial + (size_t)(b * split + sp) * 64 * 256;
    #pragma unroll
    for (int ct = 0; ct < 16; ++ct) {
        #pragma unroll
        for (int r = 0; r < 4; ++r) {
            int k = w * 16 + quad * 4 + r;
            dst[k * 256 + ct * 16 + m] = acc[ct][r];
        }
    }
    atomicAdd(S + b * 64 + lane, sacc);
}

// ---------------- Phase 4a: reduce partials, subtract S*centroid, intra-normalize ----------------
__global__ __launch_bounds__(256) void p4a_vlad(
    const float* __restrict__ partial, const float* __restrict__ S,
    const float* __restrict__ cents, float* __restrict__ v, int split)
{
    const int b = blockIdx.x >> 6, k = blockIdx.x & 63;
    const int t = threadIdx.x;
    float sum = 0.f;
    const float* base = partial + ((size_t)(b * split) * 64 + k) * 256 + t;
    for (int sp = 0; sp < split; ++sp)
        sum += base[(size_t)sp * 64 * 256];
    float val = sum - S[b * 64 + k] * cents[k * 256 + t];
    float sq = val * val;
    #pragma unroll
    for (int off = 32; off >= 1; off >>= 1) sq += __shfl_xor(sq, off);
    __shared__ float wsum[4];
    if ((t & 63) == 0) wsum[t >> 6] = sq;
    __syncthreads();
    float tot = wsum[0] + wsum[1] + wsum[2] + wsum[3];
    float r = 1.0f / fmaxf(sqrtf(tot), 1e-12f);
    v[b * 16384 + k * 256 + t] = val * r;
}

// ---------------- Phase 4b: FC out = v @ fc_w.T + fc_b ----------------
__global__ __launch_bounds__(256) void p4b_fc(
    const float* __restrict__ v, const float* __restrict__ fcw,
    const float* __restrict__ fcb, float* __restrict__ pre)
{
    const int t = threadIdx.x;
    const int o0 = blockIdx.x * 4;
    float acc[4][8] = {};
    for (int it = 0; it < 64; ++it) {
        int i = it * 256 + t;
        float wv[4];
        #pragma unroll
        for (int oo = 0; oo < 4; ++oo) wv[oo] = fcw[(size_t)(o0 + oo) * 16384 + i];
        #pragma unroll
        for (int b = 0; b < 8; ++b) {
            float vv = v[b * 16384 + i];
            #pragma unroll
            for (int oo = 0; oo < 4; ++oo) acc[oo][b] += wv[oo] * vv;
        }
    }
    __shared__ float red[32][4];
    #pragma unroll
    for (int oo = 0; oo < 4; ++oo)
        #pragma unroll
        for (int b = 0; b < 8; ++b) {
            float sv = acc[oo][b];
            #pragma unroll
            for (int off = 32; off >= 1; off >>= 1) sv += __shfl_xor(sv, off);
            if ((t & 63) == 0) red[oo * 8 + b][t >> 6] = sv;
        }
    __syncthreads();
    if (t < 32) {
        int oo = t >> 3, b = t & 7;
        float sv = red[t][0] + red[t][1] + red[t][2] + red[t][3];
        pre[b * 1024 + o0 + oo] = sv + fcb[o0 + oo];
    }
}

// ---------------- Phase 5: final l2norm over 1024 ----------------
__global__ __launch_bounds__(256) void p5_norm(const float* __restrict__ pre, float* __restrict__ out)
{
    const int b = blockIdx.x, t = threadIdx.x;
    float vals[4];
    float sq = 0.f;
    #pragma unroll
    for (int i = 0; i < 4; ++i) {
        vals[i] = pre[b * 1024 + t + 256 * i];
        sq += vals[i] * vals[i];
    }
    #pragma unroll
    for (int off = 32; off >= 1; off >>= 1) sq += __shfl_xor(sq, off);
    __shared__ float wsum[4];
    if ((t & 63) == 0) wsum[t >> 6] = sq;
    __syncthreads();
    float tot = wsum[0] + wsum[1] + wsum[2] + wsum[3];
    float r = 1.0f / fmaxf(sqrtf(tot), 1e-12f);
    #pragma unroll
    for (int i = 0; i < 4; ++i) out[b * 1024 + t + 256 * i] = vals[i] * r;
}

extern "C" void kernel_launch(void* const* d_in, const int* in_sizes, int n_in,
                              void* d_out, int out_size, void* d_ws, size_t ws_size,
                              hipStream_t stream)
{
    const float* feat  = (const float*)d_in[0];
    const int*   bids  = (const int*)d_in[1];
    const float* cents = (const float*)d_in[2];
    const float* convw = (const float*)d_in[3];
    const float* convb = (const float*)d_in[4];
    const float* fcw   = (const float*)d_in[5];
    const float* fcb   = (const float*)d_in[6];
    float* out = (float*)d_out;

    const int N = in_sizes[0] / 256;  // 200000

    // ---- adaptive SPLIT: pick largest partial buffer that fits the workspace
    const size_t base_floats = 16384 /*whi/wlo as shorts = 16384 floats*/
                             + (size_t)N * 64 /*soft*/ + N /*invn*/
                             + 512 /*S*/ + 8 * 16384 /*v*/ + 8192 /*pre*/;
    const size_t base_ints = (size_t)N + 8 + 9 + 8;
    int split = 96;
    while (split > 16) {
        size_t tot = (base_floats + (size_t)split * 8 * 16384) * 4 + base_ints * 4;
        if (tot <= ws_size) break;
        split -= 16;
    }

    short* whi = (short*)d_ws;                    // 16384 shorts
    short* wlo = whi + 16384;                     // 16384 shorts
    float* soft = (float*)(wlo + 16384);          // N*64
    float* invn = soft + (size_t)N * 64;          // N
    float* partial = invn + N;                    // split*8*64*256
    float* S    = partial + (size_t)split * 8 * 16384;  // 512
    float* v    = S + 512;                        // 8*16384
    float* pre  = v + 8 * 16384;                  // 8192
    int* perm = (int*)(pre + 8192);               // N
    int* cnts = perm + N;                         // 8
    int* offs = cnts + 8;                         // 9
    int* cur  = offs + 9;                         // 8

    hipMemsetAsync(S, 0, 512 * sizeof(float), stream);
    hipMemsetAsync(cnts, 0, 8 * sizeof(int), stream);

    p0_wsplit<<<8, 256, 0, stream>>>(convw, whi, wlo);
    p1_mfma<<<(N + 63) / 64, 256, 0, stream>>>(feat, bids, whi, wlo, convb, soft, invn, cnts, N);
    p2_offsets<<<1, 64, 0, stream>>>(cnts, offs, cur);
    p2_scatter<<<(N + 255) / 256, 256, 0, stream>>>(bids, cur, perm, N);
    p3_mfma<<<8 * split, 256, 0, stream>>>(feat, soft, invn, perm, offs, partial, S, split);
    p4a_vlad<<<512, 256, 0, stream>>>(partial, S, cents, v, split);
    p4b_fc<<<256, 256, 0, stream>>>(v, fcw, fcb, pre);
    p5_norm<<<8, 256, 0, stream>>>(pre, out);
}

// Round 4
// 481.002 us; speedup vs baseline: 1.2110x; 1.1419x over previous
//
#include <hip/hip_runtime.h>
#include <hip/hip_bf16.h>

typedef __attribute__((ext_vector_type(8))) short bf16x8;
typedef __attribute__((ext_vector_type(4))) float f32x4;

#define PCAP 768   // max points per p3 block (batch_len/split + slack)

// async 16B global->LDS copy (per-lane global src, wave-uniform LDS base + lane*16)
__device__ __forceinline__ void async_copy16(const void* g, void* l)
{
    __builtin_amdgcn_global_load_lds(
        (const __attribute__((address_space(1))) unsigned int*)g,
        (__attribute__((address_space(3))) unsigned int*)l, 16, 0, 0);
}

// ---------------- Phase 0: pre-split conv_w into frag-ready hi/lo bf16 ----------------
__global__ void p0_wsplit(const float* __restrict__ convw,
                          short* __restrict__ whi, short* __restrict__ wlo)
{
    int e = blockIdx.x * 256 + threadIdx.x;
    if (e >= 2048) return;
    int lane = e & 63;
    int kstep = (e >> 6) & 7;
    int nt = e >> 9;
    int cluster = nt * 16 + (lane & 15);
    int ch0 = kstep * 32 + (lane >> 4) * 8;
    const float* src = convw + cluster * 256 + ch0;
    #pragma unroll
    for (int j = 0; j < 8; ++j) {
        float x = src[j];
        unsigned u = __float_as_uint(x);
        unsigned uh = u & 0xffff0000u;
        float r = x - __uint_as_float(uh);
        whi[e * 8 + j] = (short)(u >> 16);
        wlo[e * 8 + j] = (short)(__float_as_uint(r) >> 16);
    }
}

// ---------------- Phase 1: fused norm + logits (split-bf16 MFMA) + softmax ----------------
// feat staged to LDS via async global_load_lds, double-buffered 64pt x 64ch chunks.
// XOR-swizzled source so ds_read_b128 is bank-balanced. Weight frags loaded BEFORE the
// async stage issue (older in vmcnt order -> DMAs stay in flight across the MFMAs).
__global__ __launch_bounds__(256, 3) void p1_mfma(
    const float* __restrict__ feat, const int* __restrict__ bids,
    const short* __restrict__ whi, const short* __restrict__ wlo,
    const float* __restrict__ convb,
    float* __restrict__ soft, float* __restrict__ invn, int* __restrict__ cnts, int N)
{
    __shared__ float xbuf[2][4096];   // 2 x 16KB: 64 pts x 64 ch, swizzled
    __shared__ int cnt[8];
    const int t = threadIdx.x;
    if (t < 8) cnt[t] = 0;
    const int w = t >> 6, lane = t & 63;
    const int m = lane & 15, quad = lane >> 4;
    const int p0 = blockIdx.x * 64;

    int s_pt[4], s_inner[4];
    #pragma unroll
    for (int pass = 0; pass < 4; ++pass) {
        int slot = pass * 256 + t;
        s_pt[pass] = slot >> 4;
        s_inner[pass] = (slot & 15) ^ (s_pt[pass] & 15);
    }

    auto STAGE = [&](int bi, int ck) {
        #pragma unroll
        for (int pass = 0; pass < 4; ++pass) {
            int gpt = p0 + s_pt[pass];
            const float* src = (gpt < N)
                ? feat + (size_t)gpt * 256 + ck * 64 + s_inner[pass] * 4
                : feat;  // safe dummy row; result masked in epilogue
            async_copy16(src, (char*)&xbuf[bi][0] + (size_t)(pass * 256 + w * 64) * 16);
        }
    };

    STAGE(0, 0);
    __syncthreads();

    f32x4 acc[4];
    #pragma unroll
    for (int nt = 0; nt < 4; ++nt) acc[nt] = (f32x4){0.f, 0.f, 0.f, 0.f};
    float ssq = 0.f;

    const bf16x8* WH = (const bf16x8*)whi;
    const bf16x8* WL = (const bf16x8*)wlo;
    const int ptl = w * 16 + m;

    #pragma unroll
    for (int ck = 0; ck < 4; ++ck) {
        bf16x8 wfh[2][4], wfl[2][4];
        #pragma unroll
        for (int k2 = 0; k2 < 2; ++k2)
            #pragma unroll
            for (int nt = 0; nt < 4; ++nt) {
                wfh[k2][nt] = WH[(nt * 8 + ck * 2 + k2) * 64 + lane];
                wfl[k2][nt] = WL[(nt * 8 + ck * 2 + k2) * 64 + lane];
            }
        __builtin_amdgcn_sched_barrier(0);
        if (ck < 3) STAGE((ck + 1) & 1, ck + 1);
        __builtin_amdgcn_sched_barrier(0);

        const float* B = &xbuf[ck & 1][0];
        #pragma unroll
        for (int k2 = 0; k2 < 2; ++k2) {
            int i0 = (k2 * 8 + quad * 2 + 0) ^ m;
            int i1 = (k2 * 8 + quad * 2 + 1) ^ m;
            float4 v0 = *(const float4*)(B + (ptl * 16 + i0) * 4);
            float4 v1 = *(const float4*)(B + (ptl * 16 + i1) * 4);
            float x[8] = {v0.x, v0.y, v0.z, v0.w, v1.x, v1.y, v1.z, v1.w};
            bf16x8 ahi, alo;
            #pragma unroll
            for (int j = 0; j < 8; ++j) {
                unsigned u = __float_as_uint(x[j]);
                float r = x[j] - __uint_as_float(u & 0xffff0000u);
                ahi[j] = (short)(u >> 16);
                alo[j] = (short)(__float_as_uint(r) >> 16);
                ssq += x[j] * x[j];
            }
            #pragma unroll
            for (int nt = 0; nt < 4; ++nt) {
                acc[nt] = __builtin_amdgcn_mfma_f32_16x16x32_bf16(ahi, wfh[k2][nt], acc[nt], 0, 0, 0);
                acc[nt] = __builtin_amdgcn_mfma_f32_16x16x32_bf16(ahi, wfl[k2][nt], acc[nt], 0, 0, 0);
                acc[nt] = __builtin_amdgcn_mfma_f32_16x16x32_bf16(alo, wfh[k2][nt], acc[nt], 0, 0, 0);
            }
        }
        if (ck < 3) __syncthreads();
    }

    ssq += __shfl_xor(ssq, 16);
    ssq += __shfl_xor(ssq, 32);

    float bias[4];
    #pragma unroll
    for (int nt = 0; nt < 4; ++nt) bias[nt] = convb[nt * 16 + m];

    #pragma unroll
    for (int r = 0; r < 4; ++r) {
        int pl = quad * 4 + r;
        int gpt = p0 + w * 16 + pl;
        float sq = __shfl(ssq, pl);
        float inv = rsqrtf(fmaxf(sq, 1e-24f));
        float v[4];
        #pragma unroll
        for (int nt = 0; nt < 4; ++nt) v[nt] = acc[nt][r] * inv + bias[nt];
        float mx = fmaxf(fmaxf(v[0], v[1]), fmaxf(v[2], v[3]));
        #pragma unroll
        for (int off = 8; off >= 1; off >>= 1) mx = fmaxf(mx, __shfl_xor(mx, off));
        float e[4];
        float s = 0.f;
        #pragma unroll
        for (int nt = 0; nt < 4; ++nt) { e[nt] = __expf(v[nt] - mx); s += e[nt]; }
        #pragma unroll
        for (int off = 8; off >= 1; off >>= 1) s += __shfl_xor(s, off);
        float rs = 1.0f / s;
        if (gpt < N) {
            #pragma unroll
            for (int nt = 0; nt < 4; ++nt)
                soft[(size_t)gpt * 64 + nt * 16 + m] = e[nt] * rs;
            if (m == 0) {
                invn[gpt] = inv;
                atomicAdd(&cnt[bids[gpt]], 1);
            }
        }
    }
    __syncthreads();
    if (t < 8) atomicAdd(&cnts[t], cnt[t]);
}

// ---------------- Phase 2: prefix + counting-sort scatter ----------------
__global__ void p2_offsets(const int* __restrict__ cnts, int* __restrict__ offs, int* __restrict__ cur)
{
    if (threadIdx.x == 0) {
        int acc = 0;
        for (int b = 0; b < 8; ++b) { offs[b] = acc; cur[b] = acc; acc += cnts[b]; }
        offs[8] = acc;
    }
}

__global__ __launch_bounds__(256) void p2_scatter(
    const int* __restrict__ bids, int* __restrict__ cur, int* __restrict__ perm, int N)
{
    __shared__ int lcnt[8], lbase[8];
    const int t = threadIdx.x;
    if (t < 8) lcnt[t] = 0;
    __syncthreads();
    int p = blockIdx.x * 256 + t;
    int b = 0, my = 0;
    bool ok = p < N;
    if (ok) { b = bids[p]; my = atomicAdd(&lcnt[b], 1); }
    __syncthreads();
    if (t < 8) lbase[t] = atomicAdd(&cur[t], lcnt[t]);
    __syncthreads();
    if (ok) perm[lbase[b] + my] = p;
}

// ---------------- Phase 3: per-batch aggregation via split-bf16 MFMA ----------------
// Software-pipelined (register prefetch of next chunk's gathers overlaps the
// ds_read+MFMA phase of the current chunk, T14) + slot-XOR LDS swizzle on all tiles.
// Physical 16B slot for point-group g at row r is g^(r&3), applied on write AND read.
// launch_bounds (256,2): VGPR headroom (no spill); LDS 46KB still allows 2 blocks/CU.
__global__ __launch_bounds__(256, 2) void p3_mfma(
    const float* __restrict__ feat, const float* __restrict__ soft,
    const float* __restrict__ invn, const int* __restrict__ perm,
    const int* __restrict__ offs, float* __restrict__ partial,
    float* __restrict__ S, int split)
{
    __shared__ short xsT_hi[256 * 32];  // [c][p] 16 KB, slot-swizzled
    __shared__ short xsT_lo[256 * 32];  // 16 KB
    __shared__ short sT_hi[64 * 32];    // [k][p] 4 KB, slot-swizzled
    __shared__ short sT_lo[64 * 32];    // 4 KB
    __shared__ int   pidxL[PCAP];
    __shared__ float invL[PCAP];

    const int b  = blockIdx.x / split;
    const int sp = blockIdx.x % split;
    const int start = offs[b], end = offs[b + 1];
    const int len = end - start;
    const int chunk = (len + split - 1) / split;
    const int s0 = start + sp * chunk;
    int myLen = end - s0;
    myLen = max(0, min(myLen, chunk));
    myLen = min(myLen, PCAP);

    const int t = threadIdx.x;
    const int w = t >> 6, lane = t & 63;
    const int m = lane & 15, quad = lane >> 4;

    for (int i = t; i < myLen; i += 256) pidxL[i] = perm[s0 + i];
    __syncthreads();
    for (int i = t; i < myLen; i += 256) invL[i] = invn[pidxL[i]];
    __syncthreads();

    f32x4 acc[16];
    #pragma unroll
    for (int ct = 0; ct < 16; ++ct) acc[ct] = (f32x4){0.f, 0.f, 0.f, 0.f};
    float sacc = 0.f;

    const int nch = (myLen + 31) >> 5;

    // register prefetch state (all statically indexed)
    int   pids[8];
    float pinv[8];
    float xv[4][8];
    float sv[8];

    auto FETCH = [&](int q) {
        const int p0 = q * 32;
        #pragma unroll
        for (int j = 0; j < 8; ++j) {
            int pl = p0 + w * 8 + j;
            bool ok = pl < myLen;
            pids[j] = ok ? pidxL[pl] : -1;
            pinv[j] = ok ? invL[pl] : 0.f;
        }
        #pragma unroll
        for (int cg = 0; cg < 4; ++cg) {
            int c = cg * 64 + lane;
            #pragma unroll
            for (int j = 0; j < 8; ++j)
                xv[cg][j] = (pids[j] >= 0) ? feat[(size_t)pids[j] * 256 + c] : 0.f;
        }
        #pragma unroll
        for (int j = 0; j < 8; ++j)
            sv[j] = (pids[j] >= 0) ? soft[(size_t)pids[j] * 64 + lane] : 0.f;
    };

    if (nch > 0) FETCH(0);

    for (int q = 0; q < nch; ++q) {
        __syncthreads();   // previous chunk's LDS readers done; buffers free
        // ---- convert regs -> split bf16 and write LDS (swizzled slot = w ^ (row&3))
        #pragma unroll
        for (int cg = 0; cg < 4; ++cg) {
            int c = cg * 64 + lane;
            bf16x8 vh, vl;
            #pragma unroll
            for (int j = 0; j < 8; ++j) {
                float v = xv[cg][j] * pinv[j];
                unsigned u = __float_as_uint(v);
                float r = v - __uint_as_float(u & 0xffff0000u);
                vh[j] = (short)(u >> 16);
                vl[j] = (short)(__float_as_uint(r) >> 16);
            }
            int slot = (w ^ (c & 3)) * 8;
            *(bf16x8*)&xsT_hi[c * 32 + slot] = vh;
            *(bf16x8*)&xsT_lo[c * 32 + slot] = vl;
        }
        {
            bf16x8 vh, vl;
            #pragma unroll
            for (int j = 0; j < 8; ++j) {
                float v = sv[j];
                sacc += v;
                unsigned u = __float_as_uint(v);
                float r = v - __uint_as_float(u & 0xffff0000u);
                vh[j] = (short)(u >> 16);
                vl[j] = (short)(__float_as_uint(r) >> 16);
            }
            int slot = (w ^ (lane & 3)) * 8;
            *(bf16x8*)&sT_hi[lane * 32 + slot] = vh;
            *(bf16x8*)&sT_lo[lane * 32 + slot] = vl;
        }
        // ---- issue next chunk's global gathers NOW; they fly during the MFMA phase
        if (q + 1 < nch) FETCH(q + 1);
        __syncthreads();
        // ---- compute: A = soft^T (clusters x points), B = x (points x cols)
        {
            const int arow = w * 16 + m;
            const int aslot = (quad ^ (m & 3)) * 8;
            bf16x8 ah = *(const bf16x8*)&sT_hi[arow * 32 + aslot];
            bf16x8 al = *(const bf16x8*)&sT_lo[arow * 32 + aslot];
            const int bslot = (quad ^ (m & 3)) * 8;
            #pragma unroll
            for (int ct = 0; ct < 16; ++ct) {
                const int brow = ct * 16 + m;
                bf16x8 bh = *(const bf16x8*)&xsT_hi[brow * 32 + bslot];
                bf16x8 bl = *(const bf16x8*)&xsT_lo[brow * 32 + bslot];
                acc[ct] = __builtin_amdgcn_mfma_f32_16x16x32_bf16(ah, bh, acc[ct], 0, 0, 0);
                acc[ct] = __builtin_amdgcn_mfma_f32_16x16x32_bf16(ah, bl, acc[ct], 0, 0, 0);
                acc[ct] = __builtin_amdgcn_mfma_f32_16x16x32_bf16(al, bh, acc[ct], 0, 0, 0);
            }
        }
    }

    // ---- write this block's partial 64x256 tile (no atomics)
    float* dst = partial + (size_t)(b * split + sp) * 64 * 256;
    #pragma unroll
    for (int ct = 0; ct < 16; ++ct) {
        #pragma unroll
        for (int r = 0; r < 4; ++r) {
            int k = w * 16 + quad * 4 + r;
            dst[k * 256 + ct * 16 + m] = acc[ct][r];
        }
    }
    atomicAdd(S + b * 64 + lane, sacc);
}

// ---------------- Phase 4a: reduce partials, subtract S*centroid, intra-normalize ----------------
__global__ __launch_bounds__(256) void p4a_vlad(
    const float* __restrict__ partial, const float* __restrict__ S,
    const float* __restrict__ cents, float* __restrict__ v, int split)
{
    const int b = blockIdx.x >> 6, k = blockIdx.x & 63;
    const int t = threadIdx.x;
    float sum = 0.f;
    const float* base = partial + ((size_t)(b * split) * 64 + k) * 256 + t;
    for (int sp = 0; sp < split; ++sp)
        sum += base[(size_t)sp * 64 * 256];
    float val = sum - S[b * 64 + k] * cents[k * 256 + t];
    float sq = val * val;
    #pragma unroll
    for (int off = 32; off >= 1; off >>= 1) sq += __shfl_xor(sq, off);
    __shared__ float wsum[4];
    if ((t & 63) == 0) wsum[t >> 6] = sq;
    __syncthreads();
    float tot = wsum[0] + wsum[1] + wsum[2] + wsum[3];
    float r = 1.0f / fmaxf(sqrtf(tot), 1e-12f);
    v[b * 16384 + k * 256 + t] = val * r;
}

// ---------------- Phase 4b: FC out = v @ fc_w.T + fc_b ----------------
__global__ __launch_bounds__(256) void p4b_fc(
    const float* __restrict__ v, const float* __restrict__ fcw,
    const float* __restrict__ fcb, float* __restrict__ pre)
{
    const int t = threadIdx.x;
    const int o0 = blockIdx.x * 4;
    float acc[4][8] = {};
    for (int it = 0; it < 64; ++it) {
        int i = it * 256 + t;
        float wv[4];
        #pragma unroll
        for (int oo = 0; oo < 4; ++oo) wv[oo] = fcw[(size_t)(o0 + oo) * 16384 + i];
        #pragma unroll
        for (int b = 0; b < 8; ++b) {
            float vv = v[b * 16384 + i];
            #pragma unroll
            for (int oo = 0; oo < 4; ++oo) acc[oo][b] += wv[oo] * vv;
        }
    }
    __shared__ float red[32][4];
    #pragma unroll
    for (int oo = 0; oo < 4; ++oo)
        #pragma unroll
        for (int b = 0; b < 8; ++b) {
            float sv = acc[oo][b];
            #pragma unroll
            for (int off = 32; off >= 1; off >>= 1) sv += __shfl_xor(sv, off);
            if ((t & 63) == 0) red[oo * 8 + b][t >> 6] = sv;
        }
    __syncthreads();
    if (t < 32) {
        int oo = t >> 3, b = t & 7;
        float sv = red[t][0] + red[t][1] + red[t][2] + red[t][3];
        pre[b * 1024 + o0 + oo] = sv + fcb[o0 + oo];
    }
}

// ---------------- Phase 5: final l2norm over 1024 ----------------
__global__ __launch_bounds__(256) void p5_norm(const float* __restrict__ pre, float* __restrict__ out)
{
    const int b = blockIdx.x, t = threadIdx.x;
    float vals[4];
    float sq = 0.f;
    #pragma unroll
    for (int i = 0; i < 4; ++i) {
        vals[i] = pre[b * 1024 + t + 256 * i];
        sq += vals[i] * vals[i];
    }
    #pragma unroll
    for (int off = 32; off >= 1; off >>= 1) sq += __shfl_xor(sq, off);
    __shared__ float wsum[4];
    if ((t & 63) == 0) wsum[t >> 6] = sq;
    __syncthreads();
    float tot = wsum[0] + wsum[1] + wsum[2] + wsum[3];
    float r = 1.0f / fmaxf(sqrtf(tot), 1e-12f);
    #pragma unroll
    for (int i = 0; i < 4; ++i) out[b * 1024 + t + 256 * i] = vals[i] * r;
}

extern "C" void kernel_launch(void* const* d_in, const int* in_sizes, int n_in,
                              void* d_out, int out_size, void* d_ws, size_t ws_size,
                              hipStream_t stream)
{
    const float* feat  = (const float*)d_in[0];
    const int*   bids  = (const int*)d_in[1];
    const float* cents = (const float*)d_in[2];
    const float* convw = (const float*)d_in[3];
    const float* convb = (const float*)d_in[4];
    const float* fcw   = (const float*)d_in[5];
    const float* fcb   = (const float*)d_in[6];
    float* out = (float*)d_out;

    const int N = in_sizes[0] / 256;  // 200000

    // ---- adaptive SPLIT: pick largest partial buffer that fits the workspace
    const size_t base_floats = 16384 /*whi/wlo as shorts = 16384 floats*/
                             + (size_t)N * 64 /*soft*/ + N /*invn*/
                             + 512 /*S*/ + 8 * 16384 /*v*/ + 8192 /*pre*/;
    const size_t base_ints = (size_t)N + 8 + 9 + 8;
    int split = 96;
    while (split > 16) {
        size_t tot = (base_floats + (size_t)split * 8 * 16384) * 4 + base_ints * 4;
        if (tot <= ws_size) break;
        split -= 16;
    }

    short* whi = (short*)d_ws;                    // 16384 shorts
    short* wlo = whi + 16384;                     // 16384 shorts
    float* soft = (float*)(wlo + 16384);          // N*64
    float* invn = soft + (size_t)N * 64;          // N
    float* partial = invn + N;                    // split*8*64*256
    float* S    = partial + (size_t)split * 8 * 16384;  // 512
    float* v    = S + 512;                        // 8*16384
    float* pre  = v + 8 * 16384;                  // 8192
    int* perm = (int*)(pre + 8192);               // N
    int* cnts = perm + N;                         // 8
    int* offs = cnts + 8;                         // 9
    int* cur  = offs + 9;                         // 8

    hipMemsetAsync(S, 0, 512 * sizeof(float), stream);
    hipMemsetAsync(cnts, 0, 8 * sizeof(int), stream);

    p0_wsplit<<<8, 256, 0, stream>>>(convw, whi, wlo);
    p1_mfma<<<(N + 63) / 64, 256, 0, stream>>>(feat, bids, whi, wlo, convb, soft, invn, cnts, N);
    p2_offsets<<<1, 64, 0, stream>>>(cnts, offs, cur);
    p2_scatter<<<(N + 255) / 256, 256, 0, stream>>>(bids, cur, perm, N);
    p3_mfma<<<8 * split, 256, 0, stream>>>(feat, soft, invn, perm, offs, partial, S, split);
    p4a_vlad<<<512, 256, 0, stream>>>(partial, S, cents, v, split);
    p4b_fc<<<256, 256, 0, stream>>>(v, fcw, fcb, pre);
    p5_norm<<<8, 256, 0, stream>>>(pre, out);
}

// Round 5
// 480.958 us; speedup vs baseline: 1.2111x; 1.0001x over previous
//
#include <hip/hip_runtime.h>
#include <hip/hip_bf16.h>

typedef __attribute__((ext_vector_type(8))) short bf16x8;
typedef __attribute__((ext_vector_type(4))) float f32x4;

#define PCAP 768   // max points per p3 block (batch_len/split + slack)

// async 16B global->LDS copy (per-lane global src, wave-uniform LDS base + lane*16)
__device__ __forceinline__ void async_copy16(const void* g, void* l)
{
    __builtin_amdgcn_global_load_lds(
        (const __attribute__((address_space(1))) unsigned int*)g,
        (__attribute__((address_space(3))) unsigned int*)l, 16, 0, 0);
}

// ---------------- Phase 0: pre-split conv_w into frag-ready hi/lo bf16 ----------------
__global__ void p0_wsplit(const float* __restrict__ convw,
                          short* __restrict__ whi, short* __restrict__ wlo)
{
    int e = blockIdx.x * 256 + threadIdx.x;
    if (e >= 2048) return;
    int lane = e & 63;
    int kstep = (e >> 6) & 7;
    int nt = e >> 9;
    int cluster = nt * 16 + (lane & 15);
    int ch0 = kstep * 32 + (lane >> 4) * 8;
    const float* src = convw + cluster * 256 + ch0;
    #pragma unroll
    for (int j = 0; j < 8; ++j) {
        float x = src[j];
        unsigned u = __float_as_uint(x);
        unsigned uh = u & 0xffff0000u;
        float r = x - __uint_as_float(uh);
        whi[e * 8 + j] = (short)(u >> 16);
        wlo[e * 8 + j] = (short)(__float_as_uint(r) >> 16);
    }
}

// ---------------- Phase 1: fused norm + logits (split-bf16 MFMA) + softmax ----------------
// v3: one-wait structure. Full W (hi+lo, 64 KB) staged to LDS once via global_load_lds;
// all 16 feat float4 loads issued up front (256 B/lane in flight); single __syncthreads
// drains both. Compute loop then has only lgkm (ds_read) waits -> no per-ck stalls.
__global__ __launch_bounds__(256, 2) void p1_mfma(
    const float* __restrict__ feat, const int* __restrict__ bids,
    const short* __restrict__ whi, const short* __restrict__ wlo,
    const float* __restrict__ convb,
    float* __restrict__ soft, float* __restrict__ invn, int* __restrict__ cnts, int N)
{
    __shared__ short whL[2048 * 8];   // 32 KB: frag e=(nt*8+ks)*64+lane -> 8 shorts
    __shared__ short wlL[2048 * 8];   // 32 KB
    __shared__ int cnt[8];
    const int t = threadIdx.x;
    if (t < 8) cnt[t] = 0;
    const int w = t >> 6, lane = t & 63;
    const int m = lane & 15, quad = lane >> 4;
    const int p0 = blockIdx.x * 64;
    const int gp = p0 + w * 16 + m;
    const bool valid = gp < N;    // N = 200000 is a multiple of 64: always true, kept as safety

    // ---- stage full W into LDS (16 x 1KB-per-wave DMAs, L2-hot source)
    #pragma unroll
    for (int pass = 0; pass < 8; ++pass) {
        async_copy16((const bf16x8*)whi + pass * 256 + t,
                     (char*)whL + (size_t)(pass * 256 + w * 64) * 16);
        async_copy16((const bf16x8*)wlo + pass * 256 + t,
                     (char*)wlL + (size_t)(pass * 256 + w * 64) * 16);
    }

    // ---- issue ALL 16 feat loads (oldest in queue; 16 KB/wave in flight)
    const float* frow = valid ? (feat + (size_t)gp * 256 + quad * 8) : feat;
    float4 xv[16];
    #pragma unroll
    for (int ks = 0; ks < 8; ++ks) {
        xv[2 * ks]     = *(const float4*)(frow + ks * 32);
        xv[2 * ks + 1] = *(const float4*)(frow + ks * 32 + 4);
    }

    __syncthreads();   // single drain: W staged + all xv in registers

    f32x4 acc[4];
    #pragma unroll
    for (int nt = 0; nt < 4; ++nt) acc[nt] = (f32x4){0.f, 0.f, 0.f, 0.f};
    float ssq = 0.f;

    #pragma unroll
    for (int ks = 0; ks < 8; ++ks) {
        float x[8] = {xv[2 * ks].x, xv[2 * ks].y, xv[2 * ks].z, xv[2 * ks].w,
                      xv[2 * ks + 1].x, xv[2 * ks + 1].y, xv[2 * ks + 1].z, xv[2 * ks + 1].w};
        bf16x8 ahi, alo;
        #pragma unroll
        for (int j = 0; j < 8; ++j) {
            unsigned u = __float_as_uint(x[j]);
            float r = x[j] - __uint_as_float(u & 0xffff0000u);
            ahi[j] = (short)(u >> 16);
            alo[j] = (short)(__float_as_uint(r) >> 16);
            ssq += x[j] * x[j];
        }
        #pragma unroll
        for (int nt = 0; nt < 4; ++nt) {
            bf16x8 bh = *(const bf16x8*)&whL[(size_t)((nt * 8 + ks) * 64 + lane) * 8];
            bf16x8 bl = *(const bf16x8*)&wlL[(size_t)((nt * 8 + ks) * 64 + lane) * 8];
            acc[nt] = __builtin_amdgcn_mfma_f32_16x16x32_bf16(ahi, bh, acc[nt], 0, 0, 0);
            acc[nt] = __builtin_amdgcn_mfma_f32_16x16x32_bf16(ahi, bl, acc[nt], 0, 0, 0);
            acc[nt] = __builtin_amdgcn_mfma_f32_16x16x32_bf16(alo, bh, acc[nt], 0, 0, 0);
        }
    }

    // ---- ssq: reduce across quads; all lanes hold point (w*16+m)'s ||x||^2
    ssq += __shfl_xor(ssq, 16);
    ssq += __shfl_xor(ssq, 32);

    float bias[4];
    #pragma unroll
    for (int nt = 0; nt < 4; ++nt) bias[nt] = convb[nt * 16 + m];

    #pragma unroll
    for (int r = 0; r < 4; ++r) {
        int pl = quad * 4 + r;
        int gpt = p0 + w * 16 + pl;
        float sq = __shfl(ssq, pl);          // lane pl holds point pl's ssq
        float inv = rsqrtf(fmaxf(sq, 1e-24f));
        float v[4];
        #pragma unroll
        for (int nt = 0; nt < 4; ++nt) v[nt] = acc[nt][r] * inv + bias[nt];
        float mx = fmaxf(fmaxf(v[0], v[1]), fmaxf(v[2], v[3]));
        #pragma unroll
        for (int off = 8; off >= 1; off >>= 1) mx = fmaxf(mx, __shfl_xor(mx, off));
        float e[4];
        float s = 0.f;
        #pragma unroll
        for (int nt = 0; nt < 4; ++nt) { e[nt] = __expf(v[nt] - mx); s += e[nt]; }
        #pragma unroll
        for (int off = 8; off >= 1; off >>= 1) s += __shfl_xor(s, off);
        float rs = 1.0f / s;
        if (gpt < N) {
            #pragma unroll
            for (int nt = 0; nt < 4; ++nt)
                soft[(size_t)gpt * 64 + nt * 16 + m] = e[nt] * rs;
            if (m == 0) {
                invn[gpt] = inv;
                atomicAdd(&cnt[bids[gpt]], 1);
            }
        }
    }
    __syncthreads();
    if (t < 8) atomicAdd(&cnts[t], cnt[t]);
}

// ---------------- Phase 2: prefix + counting-sort scatter ----------------
__global__ void p2_offsets(const int* __restrict__ cnts, int* __restrict__ offs, int* __restrict__ cur)
{
    if (threadIdx.x == 0) {
        int acc = 0;
        for (int b = 0; b < 8; ++b) { offs[b] = acc; cur[b] = acc; acc += cnts[b]; }
        offs[8] = acc;
    }
}

__global__ __launch_bounds__(256) void p2_scatter(
    const int* __restrict__ bids, int* __restrict__ cur, int* __restrict__ perm, int N)
{
    __shared__ int lcnt[8], lbase[8];
    const int t = threadIdx.x;
    if (t < 8) lcnt[t] = 0;
    __syncthreads();
    int p = blockIdx.x * 256 + t;
    int b = 0, my = 0;
    bool ok = p < N;
    if (ok) { b = bids[p]; my = atomicAdd(&lcnt[b], 1); }
    __syncthreads();
    if (t < 8) lbase[t] = atomicAdd(&cur[t], lcnt[t]);
    __syncthreads();
    if (ok) perm[lbase[b] + my] = p;
}

// ---------------- Phase 3: per-batch aggregation via split-bf16 MFMA ----------------
// Software-pipelined (register prefetch of next chunk's gathers overlaps the
// ds_read+MFMA phase of the current chunk, T14) + slot-XOR LDS swizzle on all tiles.
// Physical 16B slot for point-group g at row r is g^(r&3), applied on write AND read.
__global__ __launch_bounds__(256, 2) void p3_mfma(
    const float* __restrict__ feat, const float* __restrict__ soft,
    const float* __restrict__ invn, const int* __restrict__ perm,
    const int* __restrict__ offs, float* __restrict__ partial,
    float* __restrict__ S, int split)
{
    __shared__ short xsT_hi[256 * 32];  // [c][p] 16 KB, slot-swizzled
    __shared__ short xsT_lo[256 * 32];  // 16 KB
    __shared__ short sT_hi[64 * 32];    // [k][p] 4 KB, slot-swizzled
    __shared__ short sT_lo[64 * 32];    // 4 KB
    __shared__ int   pidxL[PCAP];
    __shared__ float invL[PCAP];

    const int b  = blockIdx.x / split;
    const int sp = blockIdx.x % split;
    const int start = offs[b], end = offs[b + 1];
    const int len = end - start;
    const int chunk = (len + split - 1) / split;
    const int s0 = start + sp * chunk;
    int myLen = end - s0;
    myLen = max(0, min(myLen, chunk));
    myLen = min(myLen, PCAP);

    const int t = threadIdx.x;
    const int w = t >> 6, lane = t & 63;
    const int m = lane & 15, quad = lane >> 4;

    for (int i = t; i < myLen; i += 256) pidxL[i] = perm[s0 + i];
    __syncthreads();
    for (int i = t; i < myLen; i += 256) invL[i] = invn[pidxL[i]];
    __syncthreads();

    f32x4 acc[16];
    #pragma unroll
    for (int ct = 0; ct < 16; ++ct) acc[ct] = (f32x4){0.f, 0.f, 0.f, 0.f};
    float sacc = 0.f;

    const int nch = (myLen + 31) >> 5;

    // register prefetch state (all statically indexed)
    int   pids[8];
    float pinv[8];
    float xv[4][8];
    float sv[8];

    auto FETCH = [&](int q) {
        const int p0 = q * 32;
        #pragma unroll
        for (int j = 0; j < 8; ++j) {
            int pl = p0 + w * 8 + j;
            bool ok = pl < myLen;
            pids[j] = ok ? pidxL[pl] : -1;
            pinv[j] = ok ? invL[pl] : 0.f;
        }
        #pragma unroll
        for (int cg = 0; cg < 4; ++cg) {
            int c = cg * 64 + lane;
            #pragma unroll
            for (int j = 0; j < 8; ++j)
                xv[cg][j] = (pids[j] >= 0) ? feat[(size_t)pids[j] * 256 + c] : 0.f;
        }
        #pragma unroll
        for (int j = 0; j < 8; ++j)
            sv[j] = (pids[j] >= 0) ? soft[(size_t)pids[j] * 64 + lane] : 0.f;
    };

    if (nch > 0) FETCH(0);

    for (int q = 0; q < nch; ++q) {
        __syncthreads();   // previous chunk's LDS readers done; buffers free
        // ---- convert regs -> split bf16 and write LDS (swizzled slot = w ^ (row&3))
        #pragma unroll
        for (int cg = 0; cg < 4; ++cg) {
            int c = cg * 64 + lane;
            bf16x8 vh, vl;
            #pragma unroll
            for (int j = 0; j < 8; ++j) {
                float v = xv[cg][j] * pinv[j];
                unsigned u = __float_as_uint(v);
                float r = v - __uint_as_float(u & 0xffff0000u);
                vh[j] = (short)(u >> 16);
                vl[j] = (short)(__float_as_uint(r) >> 16);
            }
            int slot = (w ^ (c & 3)) * 8;
            *(bf16x8*)&xsT_hi[c * 32 + slot] = vh;
            *(bf16x8*)&xsT_lo[c * 32 + slot] = vl;
        }
        {
            bf16x8 vh, vl;
            #pragma unroll
            for (int j = 0; j < 8; ++j) {
                float v = sv[j];
                sacc += v;
                unsigned u = __float_as_uint(v);
                float r = v - __uint_as_float(u & 0xffff0000u);
                vh[j] = (short)(u >> 16);
                vl[j] = (short)(__float_as_uint(r) >> 16);
            }
            int slot = (w ^ (lane & 3)) * 8;
            *(bf16x8*)&sT_hi[lane * 32 + slot] = vh;
            *(bf16x8*)&sT_lo[lane * 32 + slot] = vl;
        }
        // ---- issue next chunk's global gathers NOW; they fly during the MFMA phase
        if (q + 1 < nch) FETCH(q + 1);
        __syncthreads();
        // ---- compute: A = soft^T (clusters x points), B = x (points x cols)
        {
            const int arow = w * 16 + m;
            const int aslot = (quad ^ (m & 3)) * 8;
            bf16x8 ah = *(const bf16x8*)&sT_hi[arow * 32 + aslot];
            bf16x8 al = *(const bf16x8*)&sT_lo[arow * 32 + aslot];
            const int bslot = (quad ^ (m & 3)) * 8;
            #pragma unroll
            for (int ct = 0; ct < 16; ++ct) {
                const int brow = ct * 16 + m;
                bf16x8 bh = *(const bf16x8*)&xsT_hi[brow * 32 + bslot];
                bf16x8 bl = *(const bf16x8*)&xsT_lo[brow * 32 + bslot];
                acc[ct] = __builtin_amdgcn_mfma_f32_16x16x32_bf16(ah, bh, acc[ct], 0, 0, 0);
                acc[ct] = __builtin_amdgcn_mfma_f32_16x16x32_bf16(ah, bl, acc[ct], 0, 0, 0);
                acc[ct] = __builtin_amdgcn_mfma_f32_16x16x32_bf16(al, bh, acc[ct], 0, 0, 0);
            }
        }
    }

    // ---- write this block's partial 64x256 tile (no atomics)
    float* dst = partial + (size_t)(b * split + sp) * 64 * 256;
    #pragma unroll
    for (int ct = 0; ct < 16; ++ct) {
        #pragma unroll
        for (int r = 0; r < 4; ++r) {
            int k = w * 16 + quad * 4 + r;
            dst[k * 256 + ct * 16 + m] = acc[ct][r];
        }
    }
    atomicAdd(S + b * 64 + lane, sacc);
}

// ---------------- Phase 4a: reduce partials, subtract S*centroid, intra-normalize ----------------
__global__ __launch_bounds__(256) void p4a_vlad(
    const float* __restrict__ partial, const float* __restrict__ S,
    const float* __restrict__ cents, float* __restrict__ v, int split)
{
    const int b = blockIdx.x >> 6, k = blockIdx.x & 63;
    const int t = threadIdx.x;
    float sum = 0.f;
    const float* base = partial + ((size_t)(b * split) * 64 + k) * 256 + t;
    for (int sp = 0; sp < split; ++sp)
        sum += base[(size_t)sp * 64 * 256];
    float val = sum - S[b * 64 + k] * cents[k * 256 + t];
    float sq = val * val;
    #pragma unroll
    for (int off = 32; off >= 1; off >>= 1) sq += __shfl_xor(sq, off);
    __shared__ float wsum[4];
    if ((t & 63) == 0) wsum[t >> 6] = sq;
    __syncthreads();
    float tot = wsum[0] + wsum[1] + wsum[2] + wsum[3];
    float r = 1.0f / fmaxf(sqrtf(tot), 1e-12f);
    v[b * 16384 + k * 256 + t] = val * r;
}

// ---------------- Phase 4b: FC out = v @ fc_w.T + fc_b ----------------
__global__ __launch_bounds__(256) void p4b_fc(
    const float* __restrict__ v, const float* __restrict__ fcw,
    const float* __restrict__ fcb, float* __restrict__ pre)
{
    const int t = threadIdx.x;
    const int o0 = blockIdx.x * 4;
    float acc[4][8] = {};
    for (int it = 0; it < 64; ++it) {
        int i = it * 256 + t;
        float wv[4];
        #pragma unroll
        for (int oo = 0; oo < 4; ++oo) wv[oo] = fcw[(size_t)(o0 + oo) * 16384 + i];
        #pragma unroll
        for (int b = 0; b < 8; ++b) {
            float vv = v[b * 16384 + i];
            #pragma unroll
            for (int oo = 0; oo < 4; ++oo) acc[oo][b] += wv[oo] * vv;
        }
    }
    __shared__ float red[32][4];
    #pragma unroll
    for (int oo = 0; oo < 4; ++oo)
        #pragma unroll
        for (int b = 0; b < 8; ++b) {
            float sv = acc[oo][b];
            #pragma unroll
            for (int off = 32; off >= 1; off >>= 1) sv += __shfl_xor(sv, off);
            if ((t & 63) == 0) red[oo * 8 + b][t >> 6] = sv;
        }
    __syncthreads();
    if (t < 32) {
        int oo = t >> 3, b = t & 7;
        float sv = red[t][0] + red[t][1] + red[t][2] + red[t][3];
        pre[b * 1024 + o0 + oo] = sv + fcb[o0 + oo];
    }
}

// ---------------- Phase 5: final l2norm over 1024 ----------------
__global__ __launch_bounds__(256) void p5_norm(const float* __restrict__ pre, float* __restrict__ out)
{
    const int b = blockIdx.x, t = threadIdx.x;
    float vals[4];
    float sq = 0.f;
    #pragma unroll
    for (int i = 0; i < 4; ++i) {
        vals[i] = pre[b * 1024 + t + 256 * i];
        sq += vals[i] * vals[i];
    }
    #pragma unroll
    for (int off = 32; off >= 1; off >>= 1) sq += __shfl_xor(sq, off);
    __shared__ float wsum[4];
    if ((t & 63) == 0) wsum[t >> 6] = sq;
    __syncthreads();
    float tot = wsum[0] + wsum[1] + wsum[2] + wsum[3];
    float r = 1.0f / fmaxf(sqrtf(tot), 1e-12f);
    #pragma unroll
    for (int i = 0; i < 4; ++i) out[b * 1024 + t + 256 * i] = vals[i] * r;
}

extern "C" void kernel_launch(void* const* d_in, const int* in_sizes, int n_in,
                              void* d_out, int out_size, void* d_ws, size_t ws_size,
                              hipStream_t stream)
{
    const float* feat  = (const float*)d_in[0];
    const int*   bids  = (const int*)d_in[1];
    const float* cents = (const float*)d_in[2];
    const float* convw = (const float*)d_in[3];
    const float* convb = (const float*)d_in[4];
    const float* fcw   = (const float*)d_in[5];
    const float* fcb   = (const float*)d_in[6];
    float* out = (float*)d_out;

    const int N = in_sizes[0] / 256;  // 200000

    // ---- adaptive SPLIT: pick largest partial buffer that fits the workspace
    const size_t base_floats = 16384 /*whi/wlo as shorts = 16384 floats*/
                             + (size_t)N * 64 /*soft*/ + N /*invn*/
                             + 512 /*S*/ + 8 * 16384 /*v*/ + 8192 /*pre*/;
    const size_t base_ints = (size_t)N + 8 + 9 + 8;
    int split = 96;
    while (split > 16) {
        size_t tot = (base_floats + (size_t)split * 8 * 16384) * 4 + base_ints * 4;
        if (tot <= ws_size) break;
        split -= 16;
    }

    short* whi = (short*)d_ws;                    // 16384 shorts
    short* wlo = whi + 16384;                     // 16384 shorts
    float* soft = (float*)(wlo + 16384);          // N*64
    float* invn = soft + (size_t)N * 64;          // N
    float* partial = invn + N;                    // split*8*64*256
    float* S    = partial + (size_t)split * 8 * 16384;  // 512
    float* v    = S + 512;                        // 8*16384
    float* pre  = v + 8 * 16384;                  // 8192
    int* perm = (int*)(pre + 8192);               // N
    int* cnts = perm + N;                         // 8
    int* offs = cnts + 8;                         // 9
    int* cur  = offs + 9;                         // 8

    hipMemsetAsync(S, 0, 512 * sizeof(float), stream);
    hipMemsetAsync(cnts, 0, 8 * sizeof(int), stream);

    p0_wsplit<<<8, 256, 0, stream>>>(convw, whi, wlo);
    p1_mfma<<<(N + 63) / 64, 256, 0, stream>>>(feat, bids, whi, wlo, convb, soft, invn, cnts, N);
    p2_offsets<<<1, 64, 0, stream>>>(cnts, offs, cur);
    p2_scatter<<<(N + 255) / 256, 256, 0, stream>>>(bids, cur, perm, N);
    p3_mfma<<<8 * split, 256, 0, stream>>>(feat, soft, invn, perm, offs, partial, S, split);
    p4a_vlad<<<512, 256, 0, stream>>>(partial, S, cents, v, split);
    p4b_fc<<<256, 256, 0, stream>>>(v, fcw, fcb, pre);
    p5_norm<<<8, 256, 0, stream>>>(pre, out);
}